// Round 3
// baseline (652.228 us; speedup 1.0000x reference)
//
#include <hip/hip_runtime.h>

// DCNv1 forward via implicit GEMM on MFMA (bf16 inputs, fp32 accumulate).
// x[8,64,128,128], offset[8,18,128,128], w[64,64,3,3], bias[64] -> out[8,64,128,128]
//
// GEMM view: out[pix][oc] = sum_{ck} col[pix][ck] * wT[ck][oc],  ck = k*64 + c.
// A (col) is computed on the fly directly in mfma_f32_16x16x32_bf16 A-fragment
// layout: lane l, elem e -> row = l&15 (pixel), k_loc = (l>>4)*8 + e. Since a
// K-step of 32 covers 32 c's of ONE tap k, each lane's 8 elems share one
// bilinear weight/index set (computed once per (pixel, tap)).
// B (weights) is pre-transposed into exact fragment order in d_ws by wprep.

typedef __bf16 bf16x8 __attribute__((ext_vector_type(8)));
typedef float f32x4 __attribute__((ext_vector_type(4)));

constexpr int Bn  = 8;
constexpr int Cn  = 64;
constexpr int Hn  = 128;
constexpr int Wn  = 128;
constexpr int OCn = 64;
constexpr int Kn  = 9;
constexpr int HWn = Hn * Wn;     // 16384
constexpr int CK  = Cn * Kn;     // 576
constexpr int KSTEPS = CK / 32;  // 18

// ---- pre-kernel: w[oc][c][k] -> fragment-ordered bf16 wtb ------------------
// wtb[((s*4 + n)*64 + l)*8 + e] = w[oc=n*16+(l&15)][c=ck&63][k=ck>>6],
// ck = s*32 + (l>>4)*8 + e.
__global__ __launch_bounds__(256) void wprep_kernel(const float* __restrict__ w,
                                                    __bf16* __restrict__ wtb) {
  int t = blockIdx.x * 256 + threadIdx.x;     // t = (s*4+n)*64 + l
  if (t >= KSTEPS * 4 * 64) return;
  int l = t & 63;
  int n = (t >> 6) & 3;
  int s = t >> 8;
  int oc  = n * 16 + (l & 15);
  int ckb = s * 32 + (l >> 4) * 8;
#pragma unroll
  for (int e = 0; e < 8; ++e) {
    int ck = ckb + e;
    int k  = ck >> 6;
    int c  = ck & 63;
    wtb[t * 8 + e] = (__bf16)w[oc * CK + c * Kn + k];
  }
}

// ---- main MFMA kernel ------------------------------------------------------
// 1 wave = 32 consecutive pixels (same image row) x all 64 oc.
// acc[m][n]: m in {0,1} pixel halves, n in {0..3} oc groups of 16.
__global__ __launch_bounds__(256) void dcn_mfma_kernel(
    const float* __restrict__ x, const float* __restrict__ off,
    const __bf16* __restrict__ wtb, const float* __restrict__ bias,
    float* __restrict__ out) {
  const int wave  = (blockIdx.x * 256 + threadIdx.x) >> 6;  // 0..4095
  const int l     = threadIdx.x & 63;
  const int lr    = l & 15;   // row-in-fragment (pixel / oc index)
  const int lg    = l >> 4;   // k-group
  const int pxb   = wave * 32;
  const int b     = pxb >> 14;
  const int hwb   = pxb & (HWn - 1);
  const int ho    = hwb >> 7;
  const int wob   = hwb & (Wn - 1);   // multiple of 32; 32 px stay in one row

  const float* xb  = x + b * (Cn * HWn);
  const float* ofb = off + b * (2 * Kn * HWn) + hwb;

  const f32x4 zero = {0.f, 0.f, 0.f, 0.f};
  f32x4 acc[2][4];
#pragma unroll
  for (int m = 0; m < 2; ++m)
#pragma unroll
    for (int n = 0; n < 4; ++n) acc[m][n] = zero;

  for (int k = 0; k < Kn; ++k) {
    const int ky = k / 3, kx = k % 3;
    // Per-pixel bilinear setup, once per tap, shared by all 64 c's.
    float w00[2], w01[2], w10[2], w11[2];
    int   i00[2], i01[2], i10[2], i11[2];
#pragma unroll
    for (int m = 0; m < 2; ++m) {
      const int p  = lr + 16 * m;            // pixel within wave
      const float oy = ofb[(2 * k + 0) * HWn + p];
      const float ox = ofb[(2 * k + 1) * HWn + p];
      const float py = oy + (float)(ho - 1 + ky);
      const float px = ox + (float)(wob + p - 1 + kx);

      const float y0f = floorf(py), x0f = floorf(px);
      const float ly = py - y0f, lx = px - x0f;
      const int y0 = (int)y0f, x0 = (int)x0f;
      const int y1 = y0 + 1,  x1 = x0 + 1;

      const bool vy0 = (unsigned)y0 < (unsigned)Hn;
      const bool vy1 = (unsigned)y1 < (unsigned)Hn;
      const bool vx0 = (unsigned)x0 < (unsigned)Wn;
      const bool vx1 = (unsigned)x1 < (unsigned)Wn;

      const int y0c = min(max(y0, 0), Hn - 1), y1c = min(max(y1, 0), Hn - 1);
      const int x0c = min(max(x0, 0), Wn - 1), x1c = min(max(x1, 0), Wn - 1);

      w00[m] = (vy0 && vx0) ? (1.f - ly) * (1.f - lx) : 0.f;
      w01[m] = (vy0 && vx1) ? (1.f - ly) * lx         : 0.f;
      w10[m] = (vy1 && vx0) ? ly * (1.f - lx)         : 0.f;
      w11[m] = (vy1 && vx1) ? ly * lx                 : 0.f;
      i00[m] = y0c * Wn + x0c;  i01[m] = y0c * Wn + x1c;
      i10[m] = y1c * Wn + x0c;  i11[m] = y1c * Wn + x1c;
    }

#pragma unroll
    for (int half = 0; half < 2; ++half) {
      const int s = k * 2 + half;            // K-step index

      // B fragments: 4 coalesced 16B loads from fragment-ordered wtb (L2-hot).
      bf16x8 bf[4];
      const __bf16* wb = wtb + ((size_t)(s * 4) * 64 + l) * 8;
#pragma unroll
      for (int n = 0; n < 4; ++n)
        bf[n] = *reinterpret_cast<const bf16x8*>(wb + n * 64 * 8);

      // A fragments: bilinear-sample 8 consecutive c's per lane, per m.
      const int cbase = half * 32 + lg * 8;
      bf16x8 af[2];
#pragma unroll
      for (int m = 0; m < 2; ++m) {
        const float* xc = xb + cbase * HWn;
#pragma unroll
        for (int e = 0; e < 8; ++e) {
          const float* xp = xc + e * HWn;
          const float v = fmaf(w00[m], xp[i00[m]],
                          fmaf(w01[m], xp[i01[m]],
                          fmaf(w10[m], xp[i10[m]], w11[m] * xp[i11[m]])));
          af[m][e] = (__bf16)v;
        }
      }

#pragma unroll
      for (int m = 0; m < 2; ++m)
#pragma unroll
        for (int n = 0; n < 4; ++n)
          acc[m][n] = __builtin_amdgcn_mfma_f32_16x16x32_bf16(
              af[m], bf[n], acc[m][n], 0, 0, 0);
    }
  }

  // Epilogue: D layout col=l&15 (oc), row=(l>>4)*4+r (pixel). Add bias, store.
#pragma unroll
  for (int n = 0; n < 4; ++n) {
    const int oc = n * 16 + lr;
    const float bv = bias[oc];
    float* ob = out + b * (OCn * HWn) + oc * HWn + hwb;
#pragma unroll
    for (int m = 0; m < 2; ++m)
#pragma unroll
      for (int r = 0; r < 4; ++r)
        ob[16 * m + lg * 4 + r] = acc[m][n][r] + bv;
  }
}

// ---- fallback: round-2 direct kernel (no workspace needed) -----------------
__global__ __launch_bounds__(256) void dcn_direct_kernel(
    const float* __restrict__ x, const float* __restrict__ off,
    const float* __restrict__ wgt, const float* __restrict__ bias,
    float* __restrict__ out) {
  const int pix = blockIdx.x * 256 + threadIdx.x;
  const int b   = pix >> 14;
  const int hw  = pix & (HWn - 1);
  const int ho  = hw >> 7;
  const int wo  = hw & (Wn - 1);

  float acc[OCn];
#pragma unroll
  for (int oc = 0; oc < OCn; ++oc) acc[oc] = bias[oc];

  const float* xb  = x + b * (Cn * HWn);
  const float* ofb = off + b * (2 * Kn * HWn) + hw;

  for (int k = 0; k < Kn; ++k) {
    const float oy = ofb[(2 * k + 0) * HWn];
    const float ox = ofb[(2 * k + 1) * HWn];
    const float py = oy + (float)(ho - 1 + k / 3);
    const float px = ox + (float)(wo - 1 + k % 3);
    const float y0f = floorf(py), x0f = floorf(px);
    const float ly = py - y0f, lx = px - x0f;
    const int y0 = (int)y0f, x0 = (int)x0f;
    const int y1 = y0 + 1,  x1 = x0 + 1;
    const bool vy0 = (unsigned)y0 < (unsigned)Hn, vy1 = (unsigned)y1 < (unsigned)Hn;
    const bool vx0 = (unsigned)x0 < (unsigned)Wn, vx1 = (unsigned)x1 < (unsigned)Wn;
    const int y0c = min(max(y0, 0), Hn - 1), y1c = min(max(y1, 0), Hn - 1);
    const int x0c = min(max(x0, 0), Wn - 1), x1c = min(max(x1, 0), Wn - 1);
    const float w00 = (vy0 && vx0) ? (1.f - ly) * (1.f - lx) : 0.f;
    const float w01 = (vy0 && vx1) ? (1.f - ly) * lx         : 0.f;
    const float w10 = (vy1 && vx0) ? ly * (1.f - lx)         : 0.f;
    const float w11 = (vy1 && vx1) ? ly * lx                 : 0.f;
    const int i00 = y0c * Wn + x0c, i01 = y0c * Wn + x1c;
    const int i10 = y1c * Wn + x0c, i11 = y1c * Wn + x1c;
#pragma unroll 2
    for (int c = 0; c < Cn; ++c) {
      const float* xc = xb + c * HWn;
      const float v = fmaf(w00, xc[i00], fmaf(w01, xc[i01],
                      fmaf(w10, xc[i10], w11 * xc[i11])));
      const float* wrow = wgt + c * Kn + k;
#pragma unroll
      for (int oc = 0; oc < OCn; ++oc)
        acc[oc] = fmaf(v, wrow[oc * CK], acc[oc]);
    }
  }
  float* ob = out + b * (OCn * HWn) + hw;
#pragma unroll
  for (int oc = 0; oc < OCn; ++oc) ob[oc * HWn] = acc[oc];
}

extern "C" void kernel_launch(void* const* d_in, const int* in_sizes, int n_in,
                              void* d_out, int out_size, void* d_ws, size_t ws_size,
                              hipStream_t stream) {
  const float* x    = (const float*)d_in[0];
  const float* off  = (const float*)d_in[1];
  const float* wgt  = (const float*)d_in[2];
  const float* bias = (const float*)d_in[3];
  float* out        = (float*)d_out;

  const size_t wtb_bytes = (size_t)KSTEPS * 4 * 64 * 8 * sizeof(__bf16);  // 73728

  if (ws_size >= wtb_bytes) {
    __bf16* wtb = (__bf16*)d_ws;
    wprep_kernel<<<(KSTEPS * 4 * 64 + 255) / 256, 256, 0, stream>>>(wgt, wtb);
    // 131072 px / 32 px-per-wave = 4096 waves / 4 waves-per-block = 1024 blocks
    dcn_mfma_kernel<<<1024, 256, 0, stream>>>(x, off, wtb, bias, out);
  } else {
    dcn_direct_kernel<<<(Bn * HWn) / 256, 256, 0, stream>>>(x, off, wgt, bias, out);
  }
}

// Round 6
// 295.479 us; speedup vs baseline: 2.2074x; 2.2074x over previous
//
#include <hip/hip_runtime.h>

// DCNv1 forward: im2col staged in LDS (pixel-coalesced gathers) + MFMA GEMM.
// x[8,64,128,128], offset[8,18,128,128], w[64,64,3,3], bias[64] -> out[8,64,128,128]
//
// Block = 256 thr = 4 waves = one image row (128 px) x 64 oc.
// Per tap k: stage col[128px][64c] (bf16, XOR-swizzled) in LDS, double-buffered;
// 4 waves each compute 32px x 64oc via mfma_f32_16x16x32_bf16 (fp32 acc).
// B (weights) pre-formatted to fragment order in d_ws (L2-hot, 73.7 KB).

typedef __bf16 bf16x8 __attribute__((ext_vector_type(8)));
typedef float f32x4 __attribute__((ext_vector_type(4)));

constexpr int Bn  = 8;
constexpr int Cn  = 64;
constexpr int Hn  = 128;
constexpr int Wn  = 128;
constexpr int OCn = 64;
constexpr int Kn  = 9;
constexpr int HWn = Hn * Wn;     // 16384
constexpr int CK  = Cn * Kn;     // 576
constexpr int KSTEPS = CK / 32;  // 18

// ---- pre-kernel: w[oc][c][k] -> fragment-ordered bf16 wtb (same as R3) -----
// wtb[((s*4 + n)*64 + l)*8 + e] = w[oc=n*16+(l&15)][c=ck&63][k=ck>>6],
// ck = s*32 + (l>>4)*8 + e.
__global__ __launch_bounds__(256) void wprep_kernel(const float* __restrict__ w,
                                                    __bf16* __restrict__ wtb) {
  int t = blockIdx.x * 256 + threadIdx.x;
  if (t >= KSTEPS * 4 * 64) return;
  int l = t & 63;
  int n = (t >> 6) & 3;
  int s = t >> 8;
  int oc  = n * 16 + (l & 15);
  int ckb = s * 32 + (l >> 4) * 8;
#pragma unroll
  for (int e = 0; e < 8; ++e) {
    int ck = ckb + e;
    int k  = ck >> 6;
    int c  = ck & 63;
    wtb[t * 8 + e] = (__bf16)w[oc * CK + c * Kn + k];
  }
}

// ---- main kernel -----------------------------------------------------------
__global__ __launch_bounds__(256) void dcn_mfma2_kernel(
    const float* __restrict__ x, const float* __restrict__ off,
    const __bf16* __restrict__ wtb, const float* __restrict__ bias,
    float* __restrict__ out) {
  // col[buf][px][c] bf16, byte addr = px*128 + ((c*2) ^ ((px&7)<<4)). 32 KiB.
  __shared__ __bf16 colbuf[2][128 * 64];

  // XCD-bijective swizzle: 1024 blocks / 8 XCDs -> one batch image per XCD.
  const int bid = blockIdx.x;
  const int wg  = (bid & 7) * 128 + (bid >> 3);
  const int b   = wg >> 7;    // batch
  const int ho  = wg & 127;   // image row

  const int t  = threadIdx.x;
  const int px = t & 127;     // staging: pixel owned by this thread
  const int cq = t >> 7;      // staging: channel half (0: c0..31, 1: c32..63)
  const int w  = t >> 6;      // wave id 0..3 (MFMA: px base w*32)
  const int l  = t & 63;
  const int lr = l & 15;
  const int lg = l >> 4;

  const float* xb  = x + b * (Cn * HWn);
  const float* ofb = off + b * (2 * Kn * HWn) + ho * Wn;

  const f32x4 zero = {0.f, 0.f, 0.f, 0.f};
  f32x4 acc[2][4];
#pragma unroll
  for (int m = 0; m < 2; ++m)
#pragma unroll
    for (int n = 0; n < 4; ++n) acc[m][n] = zero;

  // ---- staging: col[px][cq*32 .. cq*32+31] for tap k into colbuf[buf] ----
  auto stage = [&](int k, int buf) {
    const int ky = k / 3, kx = k % 3;  // wave-uniform
    const float oy = ofb[(2 * k + 0) * HWn + px];
    const float ox = ofb[(2 * k + 1) * HWn + px];
    const float py  = oy + (float)(ho - 1 + ky);
    const float pxf = ox + (float)(px - 1 + kx);

    const float y0f = floorf(py), x0f = floorf(pxf);
    const float ly = py - y0f, lx = pxf - x0f;
    const int y0 = (int)y0f, x0 = (int)x0f;
    const int y1 = y0 + 1,  x1 = x0 + 1;
    const bool vy0 = (unsigned)y0 < (unsigned)Hn;
    const bool vy1 = (unsigned)y1 < (unsigned)Hn;
    const bool vx0 = (unsigned)x0 < (unsigned)Wn;
    const bool vx1 = (unsigned)x1 < (unsigned)Wn;
    const int y0c = min(max(y0, 0), Hn - 1), y1c = min(max(y1, 0), Hn - 1);
    const int x0c = min(max(x0, 0), Wn - 1), x1c = min(max(x1, 0), Wn - 1);
    const float w00 = (vy0 && vx0) ? (1.f - ly) * (1.f - lx) : 0.f;
    const float w01 = (vy0 && vx1) ? (1.f - ly) * lx         : 0.f;
    const float w10 = (vy1 && vx0) ? ly * (1.f - lx)         : 0.f;
    const float w11 = (vy1 && vx1) ? ly * lx                 : 0.f;
    const int i00 = y0c * Wn + x0c, i01 = y0c * Wn + x1c;
    const int i10 = y1c * Wn + x0c, i11 = y1c * Wn + x1c;

    char* lbase = (char*)(&colbuf[buf][0]) + px * 128;
    const int sw = (px & 7) << 4;
#pragma unroll
    for (int ch = 0; ch < 4; ++ch) {   // 4 chunks x 8 channels
      const float* xc = xb + (cq * 32 + ch * 8) * HWn;
      bf16x8 v;
#pragma unroll
      for (int e = 0; e < 8; ++e) {
        const float* xp = xc + e * HWn;  // gather: 64 lanes = 64 consecutive px
        const float s = fmaf(w00, xp[i00],
                        fmaf(w01, xp[i01],
                        fmaf(w10, xp[i10], w11 * xp[i11])));
        v[e] = (__bf16)s;
      }
      *reinterpret_cast<bf16x8*>(lbase + ((cq * 64 + ch * 16) ^ sw)) = v;
    }
  };

  // ---- MFMA for tap k from colbuf[buf] ----
  auto domfma = [&](int k, int buf) {
    const char* lb = (const char*)(&colbuf[buf][0]);
#pragma unroll
    for (int h = 0; h < 2; ++h) {      // two K-steps of 32 per tap
      const int s = k * 2 + h;
      bf16x8 bf[4];
      const __bf16* wb = wtb + ((size_t)(s * 4) * 64 + l) * 8;
#pragma unroll
      for (int n = 0; n < 4; ++n)
        bf[n] = *reinterpret_cast<const bf16x8*>(wb + n * 512);
      bf16x8 af[2];
#pragma unroll
      for (int m = 0; m < 2; ++m) {
        const int ap  = w * 32 + m * 16 + lr;       // pixel row in col tile
        const int cb2 = h * 64 + lg * 16;           // byte col (8 c's)
        af[m] = *reinterpret_cast<const bf16x8*>(
            lb + ap * 128 + (cb2 ^ ((ap & 7) << 4)));
      }
#pragma unroll
      for (int m = 0; m < 2; ++m)
#pragma unroll
        for (int n = 0; n < 4; ++n)
          acc[m][n] = __builtin_amdgcn_mfma_f32_16x16x32_bf16(
              af[m], bf[n], acc[m][n], 0, 0, 0);
    }
  };

  stage(0, 0);
  __syncthreads();
#pragma unroll 1
  for (int k = 0; k < Kn - 1; ++k) {
    stage(k + 1, (k + 1) & 1);   // prefetch next tap (other buffer)
    domfma(k, k & 1);
    __syncthreads();
  }
  domfma(Kn - 1, (Kn - 1) & 1);

  // ---- epilogue: D col = oc (l&15), D row = px (lg*4+r). Bias + store. ----
#pragma unroll
  for (int n = 0; n < 4; ++n) {
    const int oc = n * 16 + lr;
    const float bv = bias[oc];
    float* ob = out + b * (OCn * HWn) + oc * HWn + ho * Wn + w * 32;
#pragma unroll
    for (int m = 0; m < 2; ++m)
#pragma unroll
      for (int r = 0; r < 4; ++r)
        ob[m * 16 + lg * 4 + r] = acc[m][n][r] + bv;
  }
}

// ---- fallback: direct kernel (no workspace needed) -------------------------
__global__ __launch_bounds__(256) void dcn_direct_kernel(
    const float* __restrict__ x, const float* __restrict__ off,
    const float* __restrict__ wgt, const float* __restrict__ bias,
    float* __restrict__ out) {
  const int pix = blockIdx.x * 256 + threadIdx.x;
  const int b   = pix >> 14;
  const int hw  = pix & (HWn - 1);
  const int ho  = hw >> 7;
  const int wo  = hw & (Wn - 1);
  float acc[OCn];
#pragma unroll
  for (int oc = 0; oc < OCn; ++oc) acc[oc] = bias[oc];
  const float* xb  = x + b * (Cn * HWn);
  const float* ofb = off + b * (2 * Kn * HWn) + hw;
  for (int k = 0; k < Kn; ++k) {
    const float oy = ofb[(2 * k + 0) * HWn];
    const float ox = ofb[(2 * k + 1) * HWn];
    const float py = oy + (float)(ho - 1 + k / 3);
    const float px = ox + (float)(wo - 1 + k % 3);
    const float y0f = floorf(py), x0f = floorf(px);
    const float ly = py - y0f, lx = px - x0f;
    const int y0 = (int)y0f, x0 = (int)x0f;
    const int y1 = y0 + 1,  x1 = x0 + 1;
    const bool vy0 = (unsigned)y0 < (unsigned)Hn, vy1 = (unsigned)y1 < (unsigned)Hn;
    const bool vx0 = (unsigned)x0 < (unsigned)Wn, vx1 = (unsigned)x1 < (unsigned)Wn;
    const int y0c = min(max(y0, 0), Hn - 1), y1c = min(max(y1, 0), Hn - 1);
    const int x0c = min(max(x0, 0), Wn - 1), x1c = min(max(x1, 0), Wn - 1);
    const float w00 = (vy0 && vx0) ? (1.f - ly) * (1.f - lx) : 0.f;
    const float w01 = (vy0 && vx1) ? (1.f - ly) * lx         : 0.f;
    const float w10 = (vy1 && vx0) ? ly * (1.f - lx)         : 0.f;
    const float w11 = (vy1 && vx1) ? ly * lx                 : 0.f;
    const int i00 = y0c * Wn + x0c, i01 = y0c * Wn + x1c;
    const int i10 = y1c * Wn + x0c, i11 = y1c * Wn + x1c;
#pragma unroll 2
    for (int c = 0; c < Cn; ++c) {
      const float* xc = xb + c * HWn;
      const float v = fmaf(w00, xc[i00], fmaf(w01, xc[i01],
                      fmaf(w10, xc[i10], w11 * xc[i11])));
      const float* wrow = wgt + c * Kn + k;
#pragma unroll
      for (int oc = 0; oc < OCn; ++oc)
        acc[oc] = fmaf(v, wrow[oc * CK], acc[oc]);
    }
  }
  float* ob = out + b * (OCn * HWn) + hw;
#pragma unroll
  for (int oc = 0; oc < OCn; ++oc) ob[oc * HWn] = acc[oc];
}

extern "C" void kernel_launch(void* const* d_in, const int* in_sizes, int n_in,
                              void* d_out, int out_size, void* d_ws, size_t ws_size,
                              hipStream_t stream) {
  const float* x    = (const float*)d_in[0];
  const float* off  = (const float*)d_in[1];
  const float* wgt  = (const float*)d_in[2];
  const float* bias = (const float*)d_in[3];
  float* out        = (float*)d_out;

  const size_t wtb_bytes = (size_t)KSTEPS * 4 * 64 * 8 * sizeof(__bf16);  // 73728

  if (ws_size >= wtb_bytes) {
    __bf16* wtb = (__bf16*)d_ws;
    wprep_kernel<<<(KSTEPS * 4 * 64 + 255) / 256, 256, 0, stream>>>(wgt, wtb);
    // 1024 blocks = 8 batches x 128 rows; 4 waves/block.
    dcn_mfma2_kernel<<<Bn * Hn, 256, 0, stream>>>(x, off, wtb, bias, out);
  } else {
    dcn_direct_kernel<<<(Bn * HWn) / 256, 256, 0, stream>>>(x, off, wgt, bias, out);
  }
}

// Round 7
// 190.076 us; speedup vs baseline: 3.4314x; 1.5545x over previous
//
#include <hip/hip_runtime.h>

// DCNv1 forward: NHWC-fp16 repack + LDS-staged im2col + f16 MFMA GEMM.
// x[8,64,128,128]f32, offset[8,18,128,128]f32, w[64,64,3,3]f32, bias[64]f32
//   -> out[8,64,128,128]f32
//
// Pipeline: (1) xprep: x NCHW f32 -> xT NHWC f16 (d_ws, 16.8 MB; 2.1 MB/img
// -> L2-resident per XCD). One bilinear corner = 64 ch = 128 B contiguous.
// (2) wprep: w -> f16 fragment order. (3) main: block = 1 row (128 px) x 64 oc;
// per tap stage col[128px][64c] f16 (XOR-swizzled, double-buffered) via packed
// half2 interpolation; 4 waves x mfma_f32_16x16x32_f16, fp32 accum.

typedef _Float16 f16x8 __attribute__((ext_vector_type(8)));
typedef __bf16 bf16x8 __attribute__((ext_vector_type(8)));
typedef float f32x4 __attribute__((ext_vector_type(4)));

constexpr int Bn  = 8;
constexpr int Cn  = 64;
constexpr int Hn  = 128;
constexpr int Wn  = 128;
constexpr int OCn = 64;
constexpr int Kn  = 9;
constexpr int HWn = Hn * Wn;     // 16384
constexpr int CK  = Cn * Kn;     // 576
constexpr int KSTEPS = CK / 32;  // 18

// ---- pre-kernel 1: x [B][C][H][W] f32 -> xT [B][H*W][C] f16 ---------------
__global__ __launch_bounds__(256) void xprep_kernel(const float* __restrict__ x,
                                                    _Float16* __restrict__ xT) {
  const int pix = blockIdx.x * 256 + threadIdx.x;   // 0..131071
  const int b   = pix >> 14;
  const int hw  = pix & (HWn - 1);
  const float* xp = x + (size_t)b * Cn * HWn + hw;
  _Float16 buf[Cn];
#pragma unroll
  for (int c = 0; c < Cn; ++c) buf[c] = (_Float16)xp[c * HWn];  // coalesced per c
  f16x8* dst = reinterpret_cast<f16x8*>(xT + (size_t)pix * Cn);
#pragma unroll
  for (int j = 0; j < 8; ++j) dst[j] = *reinterpret_cast<f16x8*>(&buf[j * 8]);
}

// ---- pre-kernel 2: w[oc][c][k] -> fragment-ordered f16 wtb -----------------
// wtb[((s*4 + n)*64 + l)*8 + e] = w[oc=n*16+(l&15)][c=ck&63][k=ck>>6],
// ck = s*32 + (l>>4)*8 + e.
__global__ __launch_bounds__(256) void wprep16_kernel(const float* __restrict__ w,
                                                      _Float16* __restrict__ wtb) {
  int t = blockIdx.x * 256 + threadIdx.x;
  if (t >= KSTEPS * 4 * 64) return;
  int l = t & 63;
  int n = (t >> 6) & 3;
  int s = t >> 8;
  int oc  = n * 16 + (l & 15);
  int ckb = s * 32 + (l >> 4) * 8;
#pragma unroll
  for (int e = 0; e < 8; ++e) {
    int ck = ckb + e;
    int k  = ck >> 6;
    int c  = ck & 63;
    wtb[t * 8 + e] = (_Float16)w[oc * CK + c * Kn + k];
  }
}

// ---- main kernel -----------------------------------------------------------
__global__ __launch_bounds__(256) void dcn_mfma3_kernel(
    const _Float16* __restrict__ xT, const float* __restrict__ off,
    const _Float16* __restrict__ wtb, const float* __restrict__ bias,
    float* __restrict__ out) {
  // col[buf][px][c] f16, byte addr = px*128 + ((c*2) ^ ((px&7)<<4)). 32 KiB.
  __shared__ _Float16 colbuf[2][128 * 64];

  // XCD-bijective swizzle: 1024 blocks / 8 XCDs -> one batch image per XCD.
  const int bid = blockIdx.x;
  const int wg  = (bid & 7) * 128 + (bid >> 3);
  const int b   = wg >> 7;    // batch
  const int ho  = wg & 127;   // image row

  const int t  = threadIdx.x;
  const int px = t & 127;     // staging: pixel owned by this thread
  const int cq = t >> 7;      // staging: channel half (0: c0..31, 1: c32..63)
  const int w  = t >> 6;      // wave id 0..3
  const int l  = t & 63;
  const int lr = l & 15;
  const int lg = l >> 4;

  const _Float16* xTb = xT + (size_t)b * HWn * Cn;
  const float*    ofb = off + b * (2 * Kn * HWn) + ho * Wn;

  const f32x4 zero = {0.f, 0.f, 0.f, 0.f};
  f32x4 acc[2][4];
#pragma unroll
  for (int m = 0; m < 2; ++m)
#pragma unroll
    for (int n = 0; n < 4; ++n) acc[m][n] = zero;

  // ---- stage col[px][cq*32..+31] for tap k (NHWC f16, packed interp) ----
  auto stage = [&](int k, int buf) {
    const int ky = k / 3, kx = k % 3;  // wave-uniform
    const float oy = ofb[(2 * k + 0) * HWn + px];
    const float ox = ofb[(2 * k + 1) * HWn + px];
    const float py  = oy + (float)(ho - 1 + ky);
    const float pxf = ox + (float)(px - 1 + kx);

    const float y0f = floorf(py), x0f = floorf(pxf);
    const float ly = py - y0f, lx = pxf - x0f;
    const int y0 = (int)y0f, x0 = (int)x0f;
    const int y1 = y0 + 1,  x1 = x0 + 1;
    const bool vy0 = (unsigned)y0 < (unsigned)Hn;
    const bool vy1 = (unsigned)y1 < (unsigned)Hn;
    const bool vx0 = (unsigned)x0 < (unsigned)Wn;
    const bool vx1 = (unsigned)x1 < (unsigned)Wn;
    const int y0c = min(max(y0, 0), Hn - 1), y1c = min(max(y1, 0), Hn - 1);
    const int x0c = min(max(x0, 0), Wn - 1), x1c = min(max(x1, 0), Wn - 1);
    const float w00 = (vy0 && vx0) ? (1.f - ly) * (1.f - lx) : 0.f;
    const float w01 = (vy0 && vx1) ? (1.f - ly) * lx         : 0.f;
    const float w10 = (vy1 && vx0) ? ly * (1.f - lx)         : 0.f;
    const float w11 = (vy1 && vx1) ? ly * lx                 : 0.f;

    // corner base pointers: 64 ch contiguous per (y,x); this thread's 32 ch.
    const _Float16* p00 = xTb + (size_t)((y0c << 7) + x0c) * Cn + cq * 32;
    const _Float16* p01 = xTb + (size_t)((y0c << 7) + x1c) * Cn + cq * 32;
    const _Float16* p10 = xTb + (size_t)((y1c << 7) + x0c) * Cn + cq * 32;
    const _Float16* p11 = xTb + (size_t)((y1c << 7) + x1c) * Cn + cq * 32;

    const _Float16 h00 = (_Float16)w00, h01 = (_Float16)w01;
    const _Float16 h10 = (_Float16)w10, h11 = (_Float16)w11;
    const f16x8 W00 = {h00, h00, h00, h00, h00, h00, h00, h00};
    const f16x8 W01 = {h01, h01, h01, h01, h01, h01, h01, h01};
    const f16x8 W10 = {h10, h10, h10, h10, h10, h10, h10, h10};
    const f16x8 W11 = {h11, h11, h11, h11, h11, h11, h11, h11};

    char* lbase = (char*)(&colbuf[buf][0]) + px * 128;
    const int sw = (px & 7) << 4;
#pragma unroll
    for (int j = 0; j < 4; ++j) {    // 4 x 16B chunks (8 f16 each)
      const f16x8 a = *reinterpret_cast<const f16x8*>(p00 + j * 8);
      const f16x8 bb = *reinterpret_cast<const f16x8*>(p01 + j * 8);
      const f16x8 c = *reinterpret_cast<const f16x8*>(p10 + j * 8);
      const f16x8 d = *reinterpret_cast<const f16x8*>(p11 + j * 8);
      const f16x8 r = a * W00 + bb * W01 + c * W10 + d * W11;  // v_pk_fma_f16
      *reinterpret_cast<f16x8*>(lbase + ((cq * 64 + j * 16) ^ sw)) = r;
    }
  };

  // ---- MFMA for tap k from colbuf[buf] ----
  auto domfma = [&](int k, int buf) {
    const char* lb = (const char*)(&colbuf[buf][0]);
#pragma unroll
    for (int h = 0; h < 2; ++h) {      // two K-steps of 32 per tap
      const int s = k * 2 + h;
      f16x8 bf[4];
      const _Float16* wb = wtb + ((size_t)(s * 4) * 64 + l) * 8;
#pragma unroll
      for (int n = 0; n < 4; ++n)
        bf[n] = *reinterpret_cast<const f16x8*>(wb + n * 512);
      f16x8 af[2];
#pragma unroll
      for (int m = 0; m < 2; ++m) {
        const int ap  = w * 32 + m * 16 + lr;       // pixel row in col tile
        const int cb2 = h * 64 + lg * 16;           // byte col (8 c's)
        af[m] = *reinterpret_cast<const f16x8*>(
            lb + ap * 128 + (cb2 ^ ((ap & 7) << 4)));
      }
#pragma unroll
      for (int m = 0; m < 2; ++m)
#pragma unroll
        for (int n = 0; n < 4; ++n)
          acc[m][n] = __builtin_amdgcn_mfma_f32_16x16x32_f16(
              af[m], bf[n], acc[m][n], 0, 0, 0);
    }
  };

  stage(0, 0);
  __syncthreads();
#pragma unroll 1
  for (int k = 0; k < Kn - 1; ++k) {
    stage(k + 1, (k + 1) & 1);   // prefetch next tap (other buffer)
    domfma(k, k & 1);
    __syncthreads();
  }
  domfma(Kn - 1, (Kn - 1) & 1);

  // ---- epilogue: D col = oc (l&15), D row = px (lg*4+r). Bias + store. ----
#pragma unroll
  for (int n = 0; n < 4; ++n) {
    const int oc = n * 16 + lr;
    const float bv = bias[oc];
    float* ob = out + b * (OCn * HWn) + oc * HWn + ho * Wn + w * 32;
#pragma unroll
    for (int m = 0; m < 2; ++m)
#pragma unroll
      for (int r = 0; r < 4; ++r)
        ob[m * 16 + lg * 4 + r] = acc[m][n][r] + bv;
  }
}

// ====================== fallback paths (smaller d_ws) =======================
__global__ __launch_bounds__(256) void wprep_kernel(const float* __restrict__ w,
                                                    __bf16* __restrict__ wtb) {
  int t = blockIdx.x * 256 + threadIdx.x;
  if (t >= KSTEPS * 4 * 64) return;
  int l = t & 63;
  int n = (t >> 6) & 3;
  int s = t >> 8;
  int oc  = n * 16 + (l & 15);
  int ckb = s * 32 + (l >> 4) * 8;
#pragma unroll
  for (int e = 0; e < 8; ++e) {
    int ck = ckb + e;
    int k  = ck >> 6;
    int c  = ck & 63;
    wtb[t * 8 + e] = (__bf16)w[oc * CK + c * Kn + k];
  }
}

__global__ __launch_bounds__(256) void dcn_mfma2_kernel(
    const float* __restrict__ x, const float* __restrict__ off,
    const __bf16* __restrict__ wtb, const float* __restrict__ bias,
    float* __restrict__ out) {
  __shared__ __bf16 colbuf[2][128 * 64];
  const int bid = blockIdx.x;
  const int wg  = (bid & 7) * 128 + (bid >> 3);
  const int b   = wg >> 7;
  const int ho  = wg & 127;
  const int t  = threadIdx.x;
  const int px = t & 127;
  const int cq = t >> 7;
  const int w  = t >> 6;
  const int l  = t & 63;
  const int lr = l & 15;
  const int lg = l >> 4;
  const float* xb  = x + b * (Cn * HWn);
  const float* ofb = off + b * (2 * Kn * HWn) + ho * Wn;
  const f32x4 zero = {0.f, 0.f, 0.f, 0.f};
  f32x4 acc[2][4];
#pragma unroll
  for (int m = 0; m < 2; ++m)
#pragma unroll
    for (int n = 0; n < 4; ++n) acc[m][n] = zero;

  auto stage = [&](int k, int buf) {
    const int ky = k / 3, kx = k % 3;
    const float oy = ofb[(2 * k + 0) * HWn + px];
    const float ox = ofb[(2 * k + 1) * HWn + px];
    const float py  = oy + (float)(ho - 1 + ky);
    const float pxf = ox + (float)(px - 1 + kx);
    const float y0f = floorf(py), x0f = floorf(pxf);
    const float ly = py - y0f, lx = pxf - x0f;
    const int y0 = (int)y0f, x0 = (int)x0f;
    const int y1 = y0 + 1,  x1 = x0 + 1;
    const bool vy0 = (unsigned)y0 < (unsigned)Hn;
    const bool vy1 = (unsigned)y1 < (unsigned)Hn;
    const bool vx0 = (unsigned)x0 < (unsigned)Wn;
    const bool vx1 = (unsigned)x1 < (unsigned)Wn;
    const int y0c = min(max(y0, 0), Hn - 1), y1c = min(max(y1, 0), Hn - 1);
    const int x0c = min(max(x0, 0), Wn - 1), x1c = min(max(x1, 0), Wn - 1);
    const float w00 = (vy0 && vx0) ? (1.f - ly) * (1.f - lx) : 0.f;
    const float w01 = (vy0 && vx1) ? (1.f - ly) * lx         : 0.f;
    const float w10 = (vy1 && vx0) ? ly * (1.f - lx)         : 0.f;
    const float w11 = (vy1 && vx1) ? ly * lx                 : 0.f;
    const int i00 = y0c * Wn + x0c, i01 = y0c * Wn + x1c;
    const int i10 = y1c * Wn + x0c, i11 = y1c * Wn + x1c;
    char* lbase = (char*)(&colbuf[buf][0]) + px * 128;
    const int sw = (px & 7) << 4;
#pragma unroll
    for (int ch = 0; ch < 4; ++ch) {
      const float* xc = xb + (cq * 32 + ch * 8) * HWn;
      bf16x8 v;
#pragma unroll
      for (int e = 0; e < 8; ++e) {
        const float* xp = xc + e * HWn;
        const float s = fmaf(w00, xp[i00],
                        fmaf(w01, xp[i01],
                        fmaf(w10, xp[i10], w11 * xp[i11])));
        v[e] = (__bf16)s;
      }
      *reinterpret_cast<bf16x8*>(lbase + ((cq * 64 + ch * 16) ^ sw)) = v;
    }
  };
  auto domfma = [&](int k, int buf) {
    const char* lb = (const char*)(&colbuf[buf][0]);
#pragma unroll
    for (int h = 0; h < 2; ++h) {
      const int s = k * 2 + h;
      bf16x8 bf[4];
      const __bf16* wb = wtb + ((size_t)(s * 4) * 64 + l) * 8;
#pragma unroll
      for (int n = 0; n < 4; ++n)
        bf[n] = *reinterpret_cast<const bf16x8*>(wb + n * 512);
      bf16x8 af[2];
#pragma unroll
      for (int m = 0; m < 2; ++m) {
        const int ap  = w * 32 + m * 16 + lr;
        const int cb2 = h * 64 + lg * 16;
        af[m] = *reinterpret_cast<const bf16x8*>(
            lb + ap * 128 + (cb2 ^ ((ap & 7) << 4)));
      }
#pragma unroll
      for (int m = 0; m < 2; ++m)
#pragma unroll
        for (int n = 0; n < 4; ++n)
          acc[m][n] = __builtin_amdgcn_mfma_f32_16x16x32_bf16(
              af[m], bf[n], acc[m][n], 0, 0, 0);
    }
  };
  stage(0, 0);
  __syncthreads();
#pragma unroll 1
  for (int k = 0; k < Kn - 1; ++k) {
    stage(k + 1, (k + 1) & 1);
    domfma(k, k & 1);
    __syncthreads();
  }
  domfma(Kn - 1, (Kn - 1) & 1);
#pragma unroll
  for (int n = 0; n < 4; ++n) {
    const int oc = n * 16 + lr;
    const float bv = bias[oc];
    float* ob = out + b * (OCn * HWn) + oc * HWn + ho * Wn + w * 32;
#pragma unroll
    for (int m = 0; m < 2; ++m)
#pragma unroll
      for (int r = 0; r < 4; ++r)
        ob[m * 16 + lg * 4 + r] = acc[m][n][r] + bv;
  }
}

__global__ __launch_bounds__(256) void dcn_direct_kernel(
    const float* __restrict__ x, const float* __restrict__ off,
    const float* __restrict__ wgt, const float* __restrict__ bias,
    float* __restrict__ out) {
  const int pix = blockIdx.x * 256 + threadIdx.x;
  const int b   = pix >> 14;
  const int hw  = pix & (HWn - 1);
  const int ho  = hw >> 7;
  const int wo  = hw & (Wn - 1);
  float acc[OCn];
#pragma unroll
  for (int oc = 0; oc < OCn; ++oc) acc[oc] = bias[oc];
  const float* xb  = x + b * (Cn * HWn);
  const float* ofb = off + b * (2 * Kn * HWn) + hw;
  for (int k = 0; k < Kn; ++k) {
    const float oy = ofb[(2 * k + 0) * HWn];
    const float ox = ofb[(2 * k + 1) * HWn];
    const float py = oy + (float)(ho - 1 + k / 3);
    const float px = ox + (float)(wo - 1 + k % 3);
    const float y0f = floorf(py), x0f = floorf(px);
    const float ly = py - y0f, lx = px - x0f;
    const int y0 = (int)y0f, x0 = (int)x0f;
    const int y1 = y0 + 1,  x1 = x0 + 1;
    const bool vy0 = (unsigned)y0 < (unsigned)Hn, vy1 = (unsigned)y1 < (unsigned)Hn;
    const bool vx0 = (unsigned)x0 < (unsigned)Wn, vx1 = (unsigned)x1 < (unsigned)Wn;
    const int y0c = min(max(y0, 0), Hn - 1), y1c = min(max(y1, 0), Hn - 1);
    const int x0c = min(max(x0, 0), Wn - 1), x1c = min(max(x1, 0), Wn - 1);
    const float w00 = (vy0 && vx0) ? (1.f - ly) * (1.f - lx) : 0.f;
    const float w01 = (vy0 && vx1) ? (1.f - ly) * lx         : 0.f;
    const float w10 = (vy1 && vx0) ? ly * (1.f - lx)         : 0.f;
    const float w11 = (vy1 && vx1) ? ly * lx                 : 0.f;
    const int i00 = y0c * Wn + x0c, i01 = y0c * Wn + x1c;
    const int i10 = y1c * Wn + x0c, i11 = y1c * Wn + x1c;
#pragma unroll 2
    for (int c = 0; c < Cn; ++c) {
      const float* xc = xb + c * HWn;
      const float v = fmaf(w00, xc[i00], fmaf(w01, xc[i01],
                      fmaf(w10, xc[i10], w11 * xc[i11])));
      const float* wrow = wgt + c * Kn + k;
#pragma unroll
      for (int oc = 0; oc < OCn; ++oc)
        acc[oc] = fmaf(v, wrow[oc * CK], acc[oc]);
    }
  }
  float* ob = out + b * (OCn * HWn) + hw;
#pragma unroll
  for (int oc = 0; oc < OCn; ++oc) ob[oc * HWn] = acc[oc];
}

extern "C" void kernel_launch(void* const* d_in, const int* in_sizes, int n_in,
                              void* d_out, int out_size, void* d_ws, size_t ws_size,
                              hipStream_t stream) {
  const float* x    = (const float*)d_in[0];
  const float* off  = (const float*)d_in[1];
  const float* wgt  = (const float*)d_in[2];
  const float* bias = (const float*)d_in[3];
  float* out        = (float*)d_out;

  const size_t xT_bytes  = (size_t)Bn * HWn * Cn * sizeof(_Float16);   // 16.78 MB
  const size_t wtb_bytes = (size_t)KSTEPS * 4 * 64 * 8 * 2;            // 73728 B

  if (ws_size >= xT_bytes + wtb_bytes) {
    _Float16* xT  = (_Float16*)d_ws;
    _Float16* wtb = (_Float16*)((char*)d_ws + xT_bytes);
    xprep_kernel<<<(Bn * HWn) / 256, 256, 0, stream>>>(x, xT);
    wprep16_kernel<<<(KSTEPS * 4 * 64 + 255) / 256, 256, 0, stream>>>(wgt, wtb);
    dcn_mfma3_kernel<<<Bn * Hn, 256, 0, stream>>>(xT, off, wtb, bias, out);
  } else if (ws_size >= wtb_bytes) {
    __bf16* wtb = (__bf16*)d_ws;
    wprep_kernel<<<(KSTEPS * 4 * 64 + 255) / 256, 256, 0, stream>>>(wgt, wtb);
    dcn_mfma2_kernel<<<Bn * Hn, 256, 0, stream>>>(x, off, wtb, bias, out);
  } else {
    dcn_direct_kernel<<<(Bn * HWn) / 256, 256, 0, stream>>>(x, off, wgt, bias, out);
  }
}

// Round 12
// 141.541 us; speedup vs baseline: 4.6080x; 1.3429x over previous
//
#include <hip/hip_runtime.h>

// DCNv1 forward: NHWC-f16 repack + per-lane octet corner gather + f16 MFMA.
// x[8,64,128,128]f32, offset[8,18,128,128]f32, w[64,64,3,3]f32, bias[64]f32
//   -> out[8,64,128,128]f32
//
// Main kernel: block = 256 thr = 4 waves = one image row (128 px) x 64 oc.
// Stage (per wave, its own 32 px): 4 rounds/tap; lane = (pixel p8 = l>>3,
// channel-octet cc = l&7). Each lane recomputes its pixel's bilinear params
// (no cross-lane ops at all), loads 16B from each of the 4 NHWC corners
// (one 128B line per corner is fully consumed by its 8-lane octet in one
// instruction), interpolates in f32 (R7-proven numerics), writes 16B to LDS.
// domfma/epilogue identical to R7 (passed). LDS i32x4 both sides + barriers.

typedef _Float16 f16x8 __attribute__((ext_vector_type(8)));
typedef int      i32x4 __attribute__((ext_vector_type(4)));
typedef float    f32x4 __attribute__((ext_vector_type(4)));

constexpr int Bn  = 8;
constexpr int Cn  = 64;
constexpr int Hn  = 128;
constexpr int Wn  = 128;
constexpr int OCn = 64;
constexpr int Kn  = 9;
constexpr int HWn = Hn * Wn;     // 16384
constexpr int CK  = Cn * Kn;     // 576
constexpr int KSTEPS = CK / 32;  // 18

// ---- pre-kernel 1: x [B][C][H][W] f32 -> xT [B][H*W][C] f16 ----------------
// thread = 16 channels of one pixel; 524288 threads (latency-hiding).
__global__ __launch_bounds__(256) void xprep_kernel(const float* __restrict__ x,
                                                    _Float16* __restrict__ xT) {
  const int tid = blockIdx.x * 256 + threadIdx.x;   // 0..524287
  const int pix = tid >> 2;
  const int cg  = tid & 3;                          // channel group of 16
  const float* xp = x + (size_t)(pix >> 14) * (Cn * HWn) + (pix & (HWn - 1));
  _Float16 buf[16];
#pragma unroll
  for (int j = 0; j < 16; ++j) buf[j] = (_Float16)xp[(cg * 16 + j) * HWn];
  f16x8* dst = reinterpret_cast<f16x8*>(xT + (size_t)pix * Cn + cg * 16);
  dst[0] = *reinterpret_cast<f16x8*>(&buf[0]);
  dst[1] = *reinterpret_cast<f16x8*>(&buf[8]);
}

// ---- pre-kernel 2: w[oc][c][k] -> fragment-ordered f16 wtb -----------------
// wtb[((s*4 + n)*64 + l)*8 + e] = w[oc=n*16+(l&15)][c=ck&63][k=ck>>6],
// ck = s*32 + (l>>4)*8 + e.
__global__ __launch_bounds__(256) void wprep16_kernel(const float* __restrict__ w,
                                                      _Float16* __restrict__ wtb) {
  int t = blockIdx.x * 256 + threadIdx.x;
  if (t >= KSTEPS * 4 * 64) return;
  int l = t & 63;
  int n = (t >> 6) & 3;
  int s = t >> 8;
  int oc  = n * 16 + (l & 15);
  int ckb = s * 32 + (l >> 4) * 8;
#pragma unroll
  for (int e = 0; e < 8; ++e) {
    int ck = ckb + e;
    int k  = ck >> 6;
    int c  = ck & 63;
    wtb[t * 8 + e] = (_Float16)w[oc * CK + c * Kn + k];
  }
}

// ---- main kernel -----------------------------------------------------------
__global__ __launch_bounds__(256) void dcn_mfma6_kernel(
    const _Float16* __restrict__ xT, const float* __restrict__ off,
    const _Float16* __restrict__ wtb, const float* __restrict__ bias,
    float* __restrict__ out) {
  // col[buf][px][c] f16, byte addr = px*128 + ((c*2) ^ ((px&7)<<4)). 32 KiB.
  __shared__ _Float16 colbuf[2][128 * 64];

  // XCD-bijective swizzle: 1024 blocks / 8 XCDs -> one batch image per XCD.
  const int bid = blockIdx.x;
  const int wg  = (bid & 7) * 128 + (bid >> 3);
  const int b   = wg >> 7;    // batch
  const int ho  = wg & 127;   // image row

  const int t  = threadIdx.x;
  const int w  = t >> 6;      // wave id 0..3
  const int l  = t & 63;
  const int lr = l & 15;
  const int lg = l >> 4;
  const int p8 = l >> 3;      // pixel-in-round (0..7)
  const int cc = l & 7;       // channel octet (channels cc*8..cc*8+7)

  const _Float16* xTb = xT + (size_t)b * HWn * Cn;
  const float*    ofb = off + b * (2 * Kn * HWn) + ho * Wn;

  const f32x4 zero = {0.f, 0.f, 0.f, 0.f};
  f32x4 acc[2][4];
#pragma unroll
  for (int m = 0; m < 2; ++m)
#pragma unroll
    for (int n = 0; n < 4; ++n) acc[m][n] = zero;

  // ---- stage: wave w fills colbuf[buf][w*32 .. w*32+31][0..63] for tap k ----
  // No cross-lane ops: each lane recomputes its pixel's bilinear params.
  auto stage = [&](int k, int buf) {
    const int ky = k / 3, kx = k % 3;  // wave-uniform
    char* lb = (char*)(&colbuf[buf][0]);
#pragma unroll
    for (int rr = 0; rr < 4; ++rr) {
      const int px = (w << 5) + (rr << 3) + p8;     // this lane's pixel
      const float oy = ofb[(2 * k + 0) * HWn + px];
      const float ox = ofb[(2 * k + 1) * HWn + px];
      const float py  = oy + (float)(ho - 1 + ky);
      const float pxf = ox + (float)(px - 1 + kx);

      const float y0f = floorf(py), x0f = floorf(pxf);
      const float ly = py - y0f, lx = pxf - x0f;
      const int y0 = (int)y0f, x0 = (int)x0f;
      const int y1 = y0 + 1,  x1 = x0 + 1;
      const bool vy0 = (unsigned)y0 < (unsigned)Hn;
      const bool vy1 = (unsigned)y1 < (unsigned)Hn;
      const bool vx0 = (unsigned)x0 < (unsigned)Wn;
      const bool vx1 = (unsigned)x1 < (unsigned)Wn;
      const int y0c = min(max(y0, 0), Hn - 1), y1c = min(max(y1, 0), Hn - 1);
      const int x0c = min(max(x0, 0), Wn - 1), x1c = min(max(x1, 0), Wn - 1);
      const float w00 = (vy0 && vx0) ? (1.f - ly) * (1.f - lx) : 0.f;
      const float w01 = (vy0 && vx1) ? (1.f - ly) * lx         : 0.f;
      const float w10 = (vy1 && vx0) ? ly * (1.f - lx)         : 0.f;
      const float w11 = (vy1 && vx1) ? ly * lx                 : 0.f;

      // 4 corner loads: 16B each, NHWC (one 128B line fully consumed by the
      // 8-lane octet of this pixel in a single instruction).
      const int co = cc * 8;
      const f16x8 A0 = *reinterpret_cast<const f16x8*>(
          xTb + ((((y0c << 7) + x0c) << 6) + co));
      const f16x8 A1 = *reinterpret_cast<const f16x8*>(
          xTb + ((((y0c << 7) + x1c) << 6) + co));
      const f16x8 B0 = *reinterpret_cast<const f16x8*>(
          xTb + ((((y1c << 7) + x0c) << 6) + co));
      const f16x8 B1 = *reinterpret_cast<const f16x8*>(
          xTb + ((((y1c << 7) + x1c) << 6) + co));

      f16x8 hv;
#pragma unroll
      for (int e = 0; e < 8; ++e) {
        const float v = fmaf(w00, (float)A0[e],
                        fmaf(w01, (float)A1[e],
                        fmaf(w10, (float)B0[e], w11 * (float)B1[e])));
        hv[e] = (_Float16)v;
      }
      *reinterpret_cast<i32x4*>(
          lb + px * 128 + ((cc * 16) ^ ((px & 7) << 4))) =
          __builtin_bit_cast(i32x4, hv);
    }
  };

  // ---- MFMA for tap k from colbuf[buf] (i32x4 loads, same TBAA as store) ----
  auto domfma = [&](int k, int buf) {
    const char* lb = (const char*)(&colbuf[buf][0]);
#pragma unroll
    for (int hh = 0; hh < 2; ++hh) {   // two K-steps of 32 per tap
      const int s = k * 2 + hh;
      f16x8 bf[4];
      const _Float16* wbp = wtb + ((size_t)(s * 4) * 64 + l) * 8;
#pragma unroll
      for (int n = 0; n < 4; ++n)
        bf[n] = *reinterpret_cast<const f16x8*>(wbp + n * 512);
      f16x8 af[2];
#pragma unroll
      for (int m = 0; m < 2; ++m) {
        const int ap  = w * 32 + m * 16 + lr;       // pixel row in col tile
        const int cb2 = hh * 64 + lg * 16;          // byte col (8 c's)
        const i32x4 ar = *reinterpret_cast<const i32x4*>(
            lb + ap * 128 + (cb2 ^ ((ap & 7) << 4)));
        af[m] = __builtin_bit_cast(f16x8, ar);
      }
#pragma unroll
      for (int m = 0; m < 2; ++m)
#pragma unroll
        for (int n = 0; n < 4; ++n)
          acc[m][n] = __builtin_amdgcn_mfma_f32_16x16x32_f16(
              af[m], bf[n], acc[m][n], 0, 0, 0);
    }
  };

  // R7-proven schedule: overlap stage(k+1) with mfma(k); barrier per tap.
  stage(0, 0);
  __syncthreads();
#pragma unroll 1
  for (int k = 0; k < Kn - 1; ++k) {
    stage(k + 1, (k + 1) & 1);
    domfma(k, k & 1);
    __syncthreads();
  }
  domfma(Kn - 1, (Kn - 1) & 1);

  // ---- epilogue: D col = oc (l&15), D row = px (lg*4+r). Bias + store. ----
#pragma unroll
  for (int n = 0; n < 4; ++n) {
    const int oc = n * 16 + lr;
    const float bv = bias[oc];
    float* ob = out + b * (OCn * HWn) + oc * HWn + ho * Wn + w * 32;
#pragma unroll
    for (int m = 0; m < 2; ++m)
#pragma unroll
      for (int r = 0; r < 4; ++r)
        ob[m * 16 + lg * 4 + r] = acc[m][n][r] + bv;
  }
}

// ---- fallback: fp32 direct kernel (no workspace needed) --------------------
__global__ __launch_bounds__(256) void dcn_direct_kernel(
    const float* __restrict__ x, const float* __restrict__ off,
    const float* __restrict__ wgt, const float* __restrict__ bias,
    float* __restrict__ out) {
  const int pix = blockIdx.x * 256 + threadIdx.x;
  const int b   = pix >> 14;
  const int hw  = pix & (HWn - 1);
  const int ho  = hw >> 7;
  const int wo  = hw & (Wn - 1);
  float acc[OCn];
#pragma unroll
  for (int oc = 0; oc < OCn; ++oc) acc[oc] = bias[oc];
  const float* xb  = x + b * (Cn * HWn);
  const float* ofb = off + b * (2 * Kn * HWn) + hw;
  for (int k = 0; k < Kn; ++k) {
    const float oy = ofb[(2 * k + 0) * HWn];
    const float ox = ofb[(2 * k + 1) * HWn];
    const float py = oy + (float)(ho - 1 + k / 3);
    const float px = ox + (float)(wo - 1 + k % 3);
    const float y0f = floorf(py), x0f = floorf(px);
    const float ly = py - y0f, lx = px - x0f;
    const int y0 = (int)y0f, x0 = (int)x0f;
    const int y1 = y0 + 1,  x1 = x0 + 1;
    const bool vy0 = (unsigned)y0 < (unsigned)Hn, vy1 = (unsigned)y1 < (unsigned)Hn;
    const bool vx0 = (unsigned)x0 < (unsigned)Wn, vx1 = (unsigned)x1 < (unsigned)Wn;
    const int y0c = min(max(y0, 0), Hn - 1), y1c = min(max(y1, 0), Hn - 1);
    const int x0c = min(max(x0, 0), Wn - 1), x1c = min(max(x1, 0), Wn - 1);
    const float w00 = (vy0 && vx0) ? (1.f - ly) * (1.f - lx) : 0.f;
    const float w01 = (vy0 && vx1) ? (1.f - ly) * lx         : 0.f;
    const float w10 = (vy1 && vx0) ? ly * (1.f - lx)         : 0.f;
    const float w11 = (vy1 && vx1) ? ly * lx                 : 0.f;
    const int i00 = y0c * Wn + x0c, i01 = y0c * Wn + x1c;
    const int i10 = y1c * Wn + x0c, i11 = y1c * Wn + x1c;
#pragma unroll 2
    for (int c = 0; c < Cn; ++c) {
      const float* xc = xb + c * HWn;
      const float v = fmaf(w00, xc[i00], fmaf(w01, xc[i01],
                      fmaf(w10, xc[i10], w11 * xc[i11])));
      const float* wrow = wgt + c * Kn + k;
#pragma unroll
      for (int oc = 0; oc < OCn; ++oc)
        acc[oc] = fmaf(v, wrow[oc * CK], acc[oc]);
    }
  }
  float* ob = out + b * (OCn * HWn) + hw;
#pragma unroll
  for (int oc = 0; oc < OCn; ++oc) ob[oc * HWn] = acc[oc];
}

extern "C" void kernel_launch(void* const* d_in, const int* in_sizes, int n_in,
                              void* d_out, int out_size, void* d_ws, size_t ws_size,
                              hipStream_t stream) {
  const float* x    = (const float*)d_in[0];
  const float* off  = (const float*)d_in[1];
  const float* wgt  = (const float*)d_in[2];
  const float* bias = (const float*)d_in[3];
  float* out        = (float*)d_out;

  const size_t xT_bytes  = (size_t)Bn * HWn * Cn * sizeof(_Float16);   // 16.78 MB
  const size_t wtb_bytes = (size_t)KSTEPS * 4 * 64 * 8 * 2;            // 73728 B

  if (ws_size >= xT_bytes + wtb_bytes) {
    _Float16* xT  = (_Float16*)d_ws;
    _Float16* wtb = (_Float16*)((char*)d_ws + xT_bytes);
    xprep_kernel<<<(Bn * HWn * 4) / 256, 256, 0, stream>>>(x, xT);
    wprep16_kernel<<<(KSTEPS * 4 * 64 + 255) / 256, 256, 0, stream>>>(wgt, wtb);
    dcn_mfma6_kernel<<<Bn * Hn, 256, 0, stream>>>(xT, off, wtb, bias, out);
  } else {
    dcn_direct_kernel<<<(Bn * HWn) / 256, 256, 0, stream>>>(x, off, wgt, bias, out);
  }
}